// Round 2
// 1155.593 us; speedup vs baseline: 1.0089x; 1.0089x over previous
//
#include <hip/hip_runtime.h>
#include <cmath>

#define NN 100000     // nodes
#define NE 3200000    // edges
#define CIN 602
#define CH 16
#define COUT 41
#define TB 128        // gemm rows per block (= threads per block)
#define KTL 32        // gemm k-tile
#define EPT 8         // edges per thread in hist/fill (MLP depth)

// Module-static scratch (independent of ws_size). ~33 MB total.
__device__ float g_h1[NN * CH];     // x @ W1
__device__ float g_h1b[NN * CH];    // relu(mean(agg1)+b1)
__device__ float g_agg2[NN * CH];   // layer-2 aggregation (pre-W2)
__device__ int   g_deg[NN];         // in-degree histogram
__device__ int   g_rs[NN + 1];      // CSR row_start (by dst)
__device__ int   g_cur[NN];         // fill cursors
__device__ int   g_csr[NE];         // src node per edge, grouped by dst

__device__ __forceinline__ int clamp_node(int v) {
    return v < 0 ? 0 : (v >= NN ? NN - 1 : v);
}

// ---------------- fallback: if input layout differs, just zero d_out ----------
__global__ __launch_bounds__(256) void fallback_zero_out_k(float* __restrict__ out, int n) {
    int i = blockIdx.x * blockDim.x + threadIdx.x;
    if (i < n) out[i] = 0.0f;
}

// ---------------- zero degree histogram ----------------
__global__ __launch_bounds__(256) void zero_deg_k() {
    int i = blockIdx.x * blockDim.x + threadIdx.x;
    if (i < NN) g_deg[i] = 0;
}

// ---------------- degree histogram over dst ----------------
// EPT edges per thread, unrolled: coalesced loads, then EPT independent
// fire-and-forget atomics in flight.
__global__ __launch_bounds__(256) void hist_k(const int* __restrict__ ei) {
    int base = blockIdx.x * (256 * EPT) + threadIdx.x;
    if (base + (EPT - 1) * 256 < NE) {
        int d[EPT];
#pragma unroll
        for (int i = 0; i < EPT; ++i) d[i] = clamp_node(ei[NE + base + i * 256]);
#pragma unroll
        for (int i = 0; i < EPT; ++i) atomicAdd(&g_deg[d[i]], 1);
    } else {
#pragma unroll
        for (int i = 0; i < EPT; ++i) {
            int e = base + i * 256;
            if (e < NE) atomicAdd(&g_deg[clamp_node(ei[NE + e])], 1);
        }
    }
}

// ---------------- exclusive prefix scan of g_deg -> g_rs, g_cur --------------
// Single block, 1024 threads; each owns a contiguous chunk of ~98 elements.
__global__ __launch_bounds__(1024) void scan_k() {
    const int CHUNK = (NN + 1023) / 1024;   // 98
    int t = threadIdx.x;
    int lo = t * CHUNK;
    int hi = lo + CHUNK; if (hi > NN) hi = NN;
    int sum = 0;
    for (int i = lo; i < hi; ++i) sum += g_deg[i];
    __shared__ int sh[1024];
    sh[t] = sum;
    __syncthreads();
    for (int off = 1; off < 1024; off <<= 1) {   // Hillis-Steele inclusive scan
        int v = (t >= off) ? sh[t - off] : 0;
        __syncthreads();
        sh[t] += v;
        __syncthreads();
    }
    int run = sh[t] - sum;                        // exclusive offset
    for (int i = lo; i < hi; ++i) {
        g_rs[i] = run; g_cur[i] = run;
        run += g_deg[i];
    }
    if (t == 1023) g_rs[NN] = sh[1023];           // == NE
}

// ---------------- fill CSR: csr[cur[d]++] = src ----------------
// EPT edges per thread, fully unrolled independent chains: the compiler
// issues EPT returning atomics back-to-back (one s_waitcnt for all), then
// EPT scatter stores. Breaks the load->atomic->store latency serialization
// of the 1-edge-per-thread version (ILP 1 -> ILP 8).
__global__ __launch_bounds__(256) void fill_k(const int* __restrict__ ei) {
    int base = blockIdx.x * (256 * EPT) + threadIdx.x;
    if (base + (EPT - 1) * 256 < NE) {
        int s[EPT], d[EPT], pos[EPT];
#pragma unroll
        for (int i = 0; i < EPT; ++i) {
            int e = base + i * 256;
            s[i] = clamp_node(ei[e]);
            d[i] = clamp_node(ei[NE + e]);
        }
#pragma unroll
        for (int i = 0; i < EPT; ++i) pos[i] = atomicAdd(&g_cur[d[i]], 1);
#pragma unroll
        for (int i = 0; i < EPT; ++i) g_csr[pos[i]] = s[i];
    } else {
        int s[EPT], d[EPT], pos[EPT];
#pragma unroll
        for (int i = 0; i < EPT; ++i) {
            int e = base + i * 256;
            if (e < NE) { s[i] = clamp_node(ei[e]); d[i] = clamp_node(ei[NE + e]); }
            else d[i] = -1;
        }
#pragma unroll
        for (int i = 0; i < EPT; ++i)
            if (d[i] >= 0) pos[i] = atomicAdd(&g_cur[d[i]], 1);
#pragma unroll
        for (int i = 0; i < EPT; ++i)
            if (d[i] >= 0) g_csr[pos[i]] = s[i];
    }
}

// ---------------- x @ W1 -> g_h1 ----------------
// 1 row per thread, 16 channel accs in VGPRs. x staged to LDS transposed via
// float2 (rows only 8B-aligned: 2408 % 16 == 8, float4 would fault on odd
// rows). Inner loop per kk: 1 ds_read_b32 + 16 FMA; W1 address is
// block-uniform -> s_load via scalar cache. Register-prefetch double buffer
// keeps the next tile's global loads in flight during compute.
__global__ __launch_bounds__(TB) void gemm1_k(const float* __restrict__ x,
                                              const float* __restrict__ W1) {
    __shared__ float xs[KTL][TB + 1];  // stride 129: staging stores & reads <=2-way
    const int t = threadIdx.x;
    const int l  = t & 15;             // staging lane within row: kk pair {2l,2l+1}
    const int rg = t >> 4;             // staging row group: rows rg, rg+8, ...
    const int row0 = blockIdx.x * TB;
    const int row  = row0 + t;         // compute row owned by this thread

    float acc[CH];
#pragma unroll
    for (int c = 0; c < CH; ++c) acc[c] = 0.f;

    float2 ld[16];

    // issue the 16 float2 loads for tile at k-offset kb
    auto stage_load = [&](int kb) {
#pragma unroll
        for (int p = 0; p < 16; ++p) {
            int rgl = row0 + rg + 8 * p;
            ld[p] = (rgl < NN)
                ? *reinterpret_cast<const float2*>(x + (size_t)rgl * CIN + kb + 2 * l)
                : make_float2(0.f, 0.f);
        }
    };
    // epilogue tile (kb=576): only kk<26 valid
    auto stage_load_ep = [&]() {
#pragma unroll
        for (int p = 0; p < 16; ++p) {
            int rgl = row0 + rg + 8 * p;
            ld[p] = (rgl < NN && l <= 12)
                ? *reinterpret_cast<const float2*>(x + (size_t)rgl * CIN + 576 + 2 * l)
                : make_float2(0.f, 0.f);
        }
    };
    auto stage_store = [&]() {
#pragma unroll
        for (int p = 0; p < 16; ++p) {
            int rl = rg + 8 * p;
            xs[2 * l][rl]     = ld[p].x;
            xs[2 * l + 1][rl] = ld[p].y;
        }
    };

    stage_load(0);
    for (int ti = 0; ti < 18; ++ti) {
        stage_store();
        __syncthreads();
        if (ti < 17) stage_load(KTL * (ti + 1)); else stage_load_ep();
        const int kb = KTL * ti;
#pragma unroll 8
        for (int kk = 0; kk < KTL; ++kk) {
            float xv = xs[kk][t];
            const float4* w4 = reinterpret_cast<const float4*>(W1 + (size_t)(kb + kk) * CH);
            float4 w0 = w4[0], w1 = w4[1], w2 = w4[2], w3 = w4[3];
            acc[0]  += xv * w0.x; acc[1]  += xv * w0.y; acc[2]  += xv * w0.z; acc[3]  += xv * w0.w;
            acc[4]  += xv * w1.x; acc[5]  += xv * w1.y; acc[6]  += xv * w1.z; acc[7]  += xv * w1.w;
            acc[8]  += xv * w2.x; acc[9]  += xv * w2.y; acc[10] += xv * w2.z; acc[11] += xv * w2.w;
            acc[12] += xv * w3.x; acc[13] += xv * w3.y; acc[14] += xv * w3.z; acc[15] += xv * w3.w;
        }
        __syncthreads();
    }
    // epilogue tile: kk in [0,26)
    stage_store();
    __syncthreads();
#pragma unroll 13
    for (int kk = 0; kk < 26; ++kk) {
        float xv = xs[kk][t];
        const float4* w4 = reinterpret_cast<const float4*>(W1 + (size_t)(576 + kk) * CH);
        float4 w0 = w4[0], w1 = w4[1], w2 = w4[2], w3 = w4[3];
        acc[0]  += xv * w0.x; acc[1]  += xv * w0.y; acc[2]  += xv * w0.z; acc[3]  += xv * w0.w;
        acc[4]  += xv * w1.x; acc[5]  += xv * w1.y; acc[6]  += xv * w1.z; acc[7]  += xv * w1.w;
        acc[8]  += xv * w2.x; acc[9]  += xv * w2.y; acc[10] += xv * w2.z; acc[11] += xv * w2.w;
        acc[12] += xv * w3.x; acc[13] += xv * w3.y; acc[14] += xv * w3.z; acc[15] += xv * w3.w;
    }

    if (row < NN) {
        float4* hp = reinterpret_cast<float4*>(g_h1 + (size_t)row * CH);
        hp[0] = make_float4(acc[0],  acc[1],  acc[2],  acc[3]);
        hp[1] = make_float4(acc[4],  acc[5],  acc[6],  acc[7]);
        hp[2] = make_float4(acc[8],  acc[9],  acc[10], acc[11]);
        hp[3] = make_float4(acc[12], acc[13], acc[14], acc[15]);
    }
}

// ---------------- layer-1 gather: h1b = relu(mean_{e->n} h1[src] + b1) -------
// thread = (node, channel-quad); 4 lanes per node read contiguous 64 B.
__global__ __launch_bounds__(256) void gather1_k(const float* __restrict__ b1) {
    int tid = blockIdx.x * blockDim.x + threadIdx.x;
    if (tid >= NN * 4) return;
    int node = tid >> 2, q = tid & 3;
    int start = g_rs[node], end = g_rs[node + 1];
    float4 acc = make_float4(0.f, 0.f, 0.f, 0.f);
    int e = start;
    for (; e + 1 < end; e += 2) {
        int s0 = g_csr[e], s1 = g_csr[e + 1];
        float4 a = *reinterpret_cast<const float4*>(&g_h1[(size_t)s0 * CH + (q << 2)]);
        float4 b = *reinterpret_cast<const float4*>(&g_h1[(size_t)s1 * CH + (q << 2)]);
        acc.x += a.x + b.x; acc.y += a.y + b.y;
        acc.z += a.z + b.z; acc.w += a.w + b.w;
    }
    if (e < end) {
        int s0 = g_csr[e];
        float4 a = *reinterpret_cast<const float4*>(&g_h1[(size_t)s0 * CH + (q << 2)]);
        acc.x += a.x; acc.y += a.y; acc.z += a.z; acc.w += a.w;
    }
    float inv = 1.0f / fmaxf((float)(end - start), 1.0f);
    float4 bv = reinterpret_cast<const float4*>(b1)[q];
    float4 r;
    r.x = fmaxf(acc.x * inv + bv.x, 0.f);
    r.y = fmaxf(acc.y * inv + bv.y, 0.f);
    r.z = fmaxf(acc.z * inv + bv.z, 0.f);
    r.w = fmaxf(acc.w * inv + bv.w, 0.f);
    reinterpret_cast<float4*>(g_h1b)[(size_t)node * 4 + q] = r;
}

// ---------------- layer-2 gather: agg2 = sum_{e->n} h1b[src] ----------------
__global__ __launch_bounds__(256) void gather2_k() {
    int tid = blockIdx.x * blockDim.x + threadIdx.x;
    if (tid >= NN * 4) return;
    int node = tid >> 2, q = tid & 3;
    int start = g_rs[node], end = g_rs[node + 1];
    float4 acc = make_float4(0.f, 0.f, 0.f, 0.f);
    int e = start;
    for (; e + 1 < end; e += 2) {
        int s0 = g_csr[e], s1 = g_csr[e + 1];
        float4 a = *reinterpret_cast<const float4*>(&g_h1b[(size_t)s0 * CH + (q << 2)]);
        float4 b = *reinterpret_cast<const float4*>(&g_h1b[(size_t)s1 * CH + (q << 2)]);
        acc.x += a.x + b.x; acc.y += a.y + b.y;
        acc.z += a.z + b.z; acc.w += a.w + b.w;
    }
    if (e < end) {
        int s0 = g_csr[e];
        float4 a = *reinterpret_cast<const float4*>(&g_h1b[(size_t)s0 * CH + (q << 2)]);
        acc.x += a.x; acc.y += a.y; acc.z += a.z; acc.w += a.w;
    }
    reinterpret_cast<float4*>(g_agg2)[(size_t)node * 4 + q] = acc;
}

// ---------------- out = log_softmax((agg2/deg) @ W2 + b2) ----------------
// One wave per node; lanes 0..40 own output channels.
__global__ __launch_bounds__(256) void final_k(const float* __restrict__ W2,
                                               const float* __restrict__ b2,
                                               float* __restrict__ out) {
    int gtid = blockIdx.x * blockDim.x + threadIdx.x;
    int node = gtid >> 6;
    int lane = gtid & 63;
    if (node >= NN) return;
    float inv = 1.0f / fmaxf((float)g_deg[node], 1.0f);
    float o = -INFINITY;
    if (lane < COUT) {
        float s = 0.f;
#pragma unroll
        for (int k = 0; k < CH; ++k)
            s += g_agg2[(size_t)node * CH + k] * W2[k * COUT + lane];
        o = s * inv + b2[lane];
    }
    float m = o;
#pragma unroll
    for (int off = 32; off > 0; off >>= 1) m = fmaxf(m, __shfl_xor(m, off, 64));
    float ex = (lane < COUT) ? expf(o - m) : 0.0f;
    float ssum = ex;
#pragma unroll
    for (int off = 32; off > 0; off >>= 1) ssum += __shfl_xor(ssum, off, 64);
    if (lane < COUT) out[(size_t)node * COUT + lane] = o - m - logf(ssum);
}

extern "C" void kernel_launch(void* const* d_in, const int* in_sizes, int n_in,
                              void* d_out, int out_size, void* d_ws, size_t ws_size,
                              hipStream_t stream) {
    (void)d_ws; (void)ws_size;
    float* out = (float*)d_out;

    // Validate assumed input layout; on mismatch report cleanly instead of faulting.
    const int expect[6] = {NN * CIN, 2 * NE, CIN * CH, CH, CH * COUT, COUT};
    bool ok = (n_in >= 6) && (out_size == NN * COUT);
    if (ok) {
        for (int i = 0; i < 6; ++i)
            if (in_sizes[i] != expect[i]) { ok = false; break; }
    }
    if (!ok) {
        int n = out_size > 0 ? out_size : 1;
        fallback_zero_out_k<<<(n + 255) / 256, 256, 0, stream>>>(out, n);
        return;
    }

    const float* x  = (const float*)d_in[0];
    const int*   ei = (const int*)d_in[1];
    const float* W1 = (const float*)d_in[2];
    const float* b1 = (const float*)d_in[3];
    const float* W2 = (const float*)d_in[4];
    const float* b2 = (const float*)d_in[5];

    const int EDGE_BLKS = (NE + 256 * EPT - 1) / (256 * EPT);

    zero_deg_k<<<(NN + 255) / 256, 256, 0, stream>>>();
    hist_k<<<EDGE_BLKS, 256, 0, stream>>>(ei);
    scan_k<<<1, 1024, 0, stream>>>();
    fill_k<<<EDGE_BLKS, 256, 0, stream>>>(ei);
    gemm1_k<<<(NN + TB - 1) / TB, TB, 0, stream>>>(x, W1);
    gather1_k<<<(NN * 4 + 255) / 256, 256, 0, stream>>>(b1);
    gather2_k<<<(NN * 4 + 255) / 256, 256, 0, stream>>>();
    final_k<<<(NN * 64 + 255) / 256, 256, 0, stream>>>(W2, b2, out);
}

// Round 3
// 666.120 us; speedup vs baseline: 1.7503x; 1.7348x over previous
//
#include <hip/hip_runtime.h>
#include <cmath>

#define NN 100000     // nodes
#define NE 3200000    // edges
#define CIN 602
#define CH 16
#define COUT 41
#define TB 128        // gemm rows per block (= threads per block)
#define KTL 32        // gemm k-tile

// ---- counting-sort CSR build (no global atomics) ----
#define NPB 128                             // nodes per coarse bucket (pow2: dst>>7)
#define NB  ((NN + NPB - 1) / NPB)          // 782 buckets
#define EPC 32                              // edges per thread in count/scatter
#define ECHUNK (256 * EPC)                  // 8192 edges per block
#define EB  ((NE + ECHUNK - 1) / ECHUNK)    // 391 edge-chunk blocks

// Module-static scratch (independent of ws_size). ~60 MB total.
__device__ float g_h1[NN * CH];     // x @ W1
__device__ float g_h1b[NN * CH];    // relu(mean(agg1)+b1)
__device__ float g_agg2[NN * CH];   // layer-2 aggregation (pre-W2)
__device__ int   g_deg[NN];         // in-degree
__device__ int   g_rs[NN + 1];      // CSR row_start (by dst)
__device__ int   g_csr[NE];         // src node per edge, grouped by dst
__device__ int2  g_pair[NE];        // (src,dst) pairs grouped by coarse bucket
__device__ int   g_cnt[NB * EB];    // per-(bucket,block) counts -> exclusive offsets
__device__ int   g_colsum[NB];      // edges per bucket
__device__ int   g_bbase[NB + 1];   // exclusive scan of g_colsum

__device__ __forceinline__ int clamp_node(int v) {
    return v < 0 ? 0 : (v >= NN ? NN - 1 : v);
}

// ---------------- fallback: if input layout differs, just zero d_out ----------
__global__ __launch_bounds__(256) void fallback_zero_out_k(float* __restrict__ out, int n) {
    int i = blockIdx.x * blockDim.x + threadIdx.x;
    if (i < n) out[i] = 0.0f;
}

// ---------------- pass 1: per-block histogram over coarse buckets (LDS) ------
__global__ __launch_bounds__(256) void count_k(const int* __restrict__ ei) {
    __shared__ int h[NB];
    const int t = threadIdx.x;
    for (int i = t; i < NB; i += 256) h[i] = 0;
    __syncthreads();
    const int base = blockIdx.x * ECHUNK;
#pragma unroll
    for (int j = 0; j < EPC; ++j) {
        int e = base + j * 256 + t;
        if (e < NE) {
            int d = clamp_node(ei[NE + e]);
            atomicAdd(&h[d >> 7], 1);
        }
    }
    __syncthreads();
    for (int i = t; i < NB; i += 256) g_cnt[i * EB + blockIdx.x] = h[i];
}

// ---------------- pass 2a: per-bucket scan over the 391 block counts ---------
// One block per bucket. cnt[b][blk] -> exclusive offset within bucket b;
// colsum[b] = total edges in bucket b.
__global__ __launch_bounds__(256) void scanA_k() {
    const int b = blockIdx.x;
    const int t = threadIdx.x;
    __shared__ int a[512];
    __shared__ int sh[256];
    a[t]       = (t < EB)       ? g_cnt[b * EB + t]       : 0;
    a[t + 256] = (t + 256 < EB) ? g_cnt[b * EB + t + 256] : 0;
    __syncthreads();
    int e0 = a[2 * t], e1 = a[2 * t + 1];
    int sum = e0 + e1;
    sh[t] = sum;
    __syncthreads();
    for (int off = 1; off < 256; off <<= 1) {   // Hillis-Steele inclusive
        int v = (t >= off) ? sh[t - off] : 0;
        __syncthreads();
        sh[t] += v;
        __syncthreads();
    }
    int run = sh[t] - sum;                       // exclusive offset of pair {2t,2t+1}
    if (2 * t < EB)     g_cnt[b * EB + 2 * t]     = run;
    if (2 * t + 1 < EB) g_cnt[b * EB + 2 * t + 1] = run + e0;
    if (t == 255) g_colsum[b] = sh[255];
}

// ---------------- pass 2b: scan bucket totals -> bucket bases ----------------
__global__ __launch_bounds__(1024) void scanB_k() {
    const int t = threadIdx.x;
    __shared__ int sh[1024];
    int v = (t < NB) ? g_colsum[t] : 0;
    sh[t] = v;
    __syncthreads();
    for (int off = 1; off < 1024; off <<= 1) {
        int u = (t >= off) ? sh[t - off] : 0;
        __syncthreads();
        sh[t] += u;
        __syncthreads();
    }
    if (t < NB) g_bbase[t] = sh[t] - v;          // exclusive
    if (t == 1023) {
        g_bbase[NB] = sh[1023];                  // == NE
        g_rs[NN]    = sh[1023];
    }
}

// ---------------- pass 3: scatter edges into bucket-grouped order ------------
// Each block reserves [bbase[b]+off[b][blk], ...) per bucket; ranks via LDS
// atomics only. No global atomics anywhere.
__global__ __launch_bounds__(256) void scatter_k(const int* __restrict__ ei) {
    __shared__ int lb[NB];     // absolute next-write position per bucket
    const int t = threadIdx.x;
    for (int i = t; i < NB; i += 256)
        lb[i] = g_bbase[i] + g_cnt[i * EB + blockIdx.x];
    __syncthreads();
    const int base = blockIdx.x * ECHUNK;
#pragma unroll
    for (int j = 0; j < EPC; ++j) {
        int e = base + j * 256 + t;
        if (e < NE) {
            int s = clamp_node(ei[e]);
            int d = clamp_node(ei[NE + e]);
            int p = atomicAdd(&lb[d >> 7], 1);
            g_pair[p] = make_int2(s, d);
        }
    }
}

// ---------------- pass 4: per-bucket CSR finalize (LDS hist + scan + rank) ---
// One block per bucket of 128 nodes; writes g_rs, g_deg, and the bucket's
// contiguous slice of g_csr.
__global__ __launch_bounds__(256) void build_k() {
    const int b = blockIdx.x;
    const int t = threadIdx.x;
    const int n0 = b * NPB;
    const int e0 = g_bbase[b], e1 = g_bbase[b + 1];
    __shared__ int ldeg[NPB];
    __shared__ int lrs[NPB + 1];
    __shared__ int lcur[NPB];
    if (t < NPB) ldeg[t] = 0;
    __syncthreads();
    for (int e = e0 + t; e < e1; e += 256) {
        int2 p = g_pair[e];
        atomicAdd(&ldeg[p.y - n0], 1);
    }
    __syncthreads();
    if (t == 0) {
        int run = 0;
        for (int i = 0; i < NPB; ++i) { lrs[i] = run; run += ldeg[i]; }
        lrs[NPB] = run;
    }
    __syncthreads();
    if (t < NPB) {
        int node = n0 + t;
        if (node < NN) {
            g_rs[node]  = e0 + lrs[t];
            g_deg[node] = ldeg[t];
        }
        lcur[t] = lrs[t];
    }
    __syncthreads();
    for (int e = e0 + t; e < e1; e += 256) {
        int2 p = g_pair[e];
        int r = atomicAdd(&lcur[p.y - n0], 1);
        g_csr[e0 + r] = p.x;
    }
}

// ---------------- x @ W1 -> g_h1 ----------------
// 1 row per thread, 16 channel accs in VGPRs. x staged to LDS transposed via
// float2 (rows only 8B-aligned: 2408 % 16 == 8, float4 would fault on odd
// rows). Inner loop per kk: 1 ds_read_b32 + 16 FMA; W1 address is
// block-uniform -> s_load via scalar cache. Register-prefetch double buffer
// keeps the next tile's global loads in flight during compute.
__global__ __launch_bounds__(TB) void gemm1_k(const float* __restrict__ x,
                                              const float* __restrict__ W1) {
    __shared__ float xs[KTL][TB + 1];  // stride 129: staging stores & reads <=2-way
    const int t = threadIdx.x;
    const int l  = t & 15;             // staging lane within row: kk pair {2l,2l+1}
    const int rg = t >> 4;             // staging row group: rows rg, rg+8, ...
    const int row0 = blockIdx.x * TB;
    const int row  = row0 + t;         // compute row owned by this thread

    float acc[CH];
#pragma unroll
    for (int c = 0; c < CH; ++c) acc[c] = 0.f;

    float2 ld[16];

    // issue the 16 float2 loads for tile at k-offset kb
    auto stage_load = [&](int kb) {
#pragma unroll
        for (int p = 0; p < 16; ++p) {
            int rgl = row0 + rg + 8 * p;
            ld[p] = (rgl < NN)
                ? *reinterpret_cast<const float2*>(x + (size_t)rgl * CIN + kb + 2 * l)
                : make_float2(0.f, 0.f);
        }
    };
    // epilogue tile (kb=576): only kk<26 valid
    auto stage_load_ep = [&]() {
#pragma unroll
        for (int p = 0; p < 16; ++p) {
            int rgl = row0 + rg + 8 * p;
            ld[p] = (rgl < NN && l <= 12)
                ? *reinterpret_cast<const float2*>(x + (size_t)rgl * CIN + 576 + 2 * l)
                : make_float2(0.f, 0.f);
        }
    };
    auto stage_store = [&]() {
#pragma unroll
        for (int p = 0; p < 16; ++p) {
            int rl = rg + 8 * p;
            xs[2 * l][rl]     = ld[p].x;
            xs[2 * l + 1][rl] = ld[p].y;
        }
    };

    stage_load(0);
    for (int ti = 0; ti < 18; ++ti) {
        stage_store();
        __syncthreads();
        if (ti < 17) stage_load(KTL * (ti + 1)); else stage_load_ep();
        const int kb = KTL * ti;
#pragma unroll 8
        for (int kk = 0; kk < KTL; ++kk) {
            float xv = xs[kk][t];
            const float4* w4 = reinterpret_cast<const float4*>(W1 + (size_t)(kb + kk) * CH);
            float4 w0 = w4[0], w1 = w4[1], w2 = w4[2], w3 = w4[3];
            acc[0]  += xv * w0.x; acc[1]  += xv * w0.y; acc[2]  += xv * w0.z; acc[3]  += xv * w0.w;
            acc[4]  += xv * w1.x; acc[5]  += xv * w1.y; acc[6]  += xv * w1.z; acc[7]  += xv * w1.w;
            acc[8]  += xv * w2.x; acc[9]  += xv * w2.y; acc[10] += xv * w2.z; acc[11] += xv * w2.w;
            acc[12] += xv * w3.x; acc[13] += xv * w3.y; acc[14] += xv * w3.z; acc[15] += xv * w3.w;
        }
        __syncthreads();
    }
    // epilogue tile: kk in [0,26)
    stage_store();
    __syncthreads();
#pragma unroll 13
    for (int kk = 0; kk < 26; ++kk) {
        float xv = xs[kk][t];
        const float4* w4 = reinterpret_cast<const float4*>(W1 + (size_t)(576 + kk) * CH);
        float4 w0 = w4[0], w1 = w4[1], w2 = w4[2], w3 = w4[3];
        acc[0]  += xv * w0.x; acc[1]  += xv * w0.y; acc[2]  += xv * w0.z; acc[3]  += xv * w0.w;
        acc[4]  += xv * w1.x; acc[5]  += xv * w1.y; acc[6]  += xv * w1.z; acc[7]  += xv * w1.w;
        acc[8]  += xv * w2.x; acc[9]  += xv * w2.y; acc[10] += xv * w2.z; acc[11] += xv * w2.w;
        acc[12] += xv * w3.x; acc[13] += xv * w3.y; acc[14] += xv * w3.z; acc[15] += xv * w3.w;
    }

    if (row < NN) {
        float4* hp = reinterpret_cast<float4*>(g_h1 + (size_t)row * CH);
        hp[0] = make_float4(acc[0],  acc[1],  acc[2],  acc[3]);
        hp[1] = make_float4(acc[4],  acc[5],  acc[6],  acc[7]);
        hp[2] = make_float4(acc[8],  acc[9],  acc[10], acc[11]);
        hp[3] = make_float4(acc[12], acc[13], acc[14], acc[15]);
    }
}

// ---------------- layer-1 gather: h1b = relu(mean_{e->n} h1[src] + b1) -------
// thread = (node, channel-quad); 4 lanes per node read contiguous 64 B.
__global__ __launch_bounds__(256) void gather1_k(const float* __restrict__ b1) {
    int tid = blockIdx.x * blockDim.x + threadIdx.x;
    if (tid >= NN * 4) return;
    int node = tid >> 2, q = tid & 3;
    int start = g_rs[node], end = g_rs[node + 1];
    float4 acc = make_float4(0.f, 0.f, 0.f, 0.f);
    int e = start;
    for (; e + 1 < end; e += 2) {
        int s0 = g_csr[e], s1 = g_csr[e + 1];
        float4 a = *reinterpret_cast<const float4*>(&g_h1[(size_t)s0 * CH + (q << 2)]);
        float4 b = *reinterpret_cast<const float4*>(&g_h1[(size_t)s1 * CH + (q << 2)]);
        acc.x += a.x + b.x; acc.y += a.y + b.y;
        acc.z += a.z + b.z; acc.w += a.w + b.w;
    }
    if (e < end) {
        int s0 = g_csr[e];
        float4 a = *reinterpret_cast<const float4*>(&g_h1[(size_t)s0 * CH + (q << 2)]);
        acc.x += a.x; acc.y += a.y; acc.z += a.z; acc.w += a.w;
    }
    float inv = 1.0f / fmaxf((float)(end - start), 1.0f);
    float4 bv = reinterpret_cast<const float4*>(b1)[q];
    float4 r;
    r.x = fmaxf(acc.x * inv + bv.x, 0.f);
    r.y = fmaxf(acc.y * inv + bv.y, 0.f);
    r.z = fmaxf(acc.z * inv + bv.z, 0.f);
    r.w = fmaxf(acc.w * inv + bv.w, 0.f);
    reinterpret_cast<float4*>(g_h1b)[(size_t)node * 4 + q] = r;
}

// ---------------- layer-2 gather: agg2 = sum_{e->n} h1b[src] ----------------
__global__ __launch_bounds__(256) void gather2_k() {
    int tid = blockIdx.x * blockDim.x + threadIdx.x;
    if (tid >= NN * 4) return;
    int node = tid >> 2, q = tid & 3;
    int start = g_rs[node], end = g_rs[node + 1];
    float4 acc = make_float4(0.f, 0.f, 0.f, 0.f);
    int e = start;
    for (; e + 1 < end; e += 2) {
        int s0 = g_csr[e], s1 = g_csr[e + 1];
        float4 a = *reinterpret_cast<const float4*>(&g_h1b[(size_t)s0 * CH + (q << 2)]);
        float4 b = *reinterpret_cast<const float4*>(&g_h1b[(size_t)s1 * CH + (q << 2)]);
        acc.x += a.x + b.x; acc.y += a.y + b.y;
        acc.z += a.z + b.z; acc.w += a.w + b.w;
    }
    if (e < end) {
        int s0 = g_csr[e];
        float4 a = *reinterpret_cast<const float4*>(&g_h1b[(size_t)s0 * CH + (q << 2)]);
        acc.x += a.x; acc.y += a.y; acc.z += a.z; acc.w += a.w;
    }
    reinterpret_cast<float4*>(g_agg2)[(size_t)node * 4 + q] = acc;
}

// ---------------- out = log_softmax((agg2/deg) @ W2 + b2) ----------------
// One wave per node; lanes 0..40 own output channels.
__global__ __launch_bounds__(256) void final_k(const float* __restrict__ W2,
                                               const float* __restrict__ b2,
                                               float* __restrict__ out) {
    int gtid = blockIdx.x * blockDim.x + threadIdx.x;
    int node = gtid >> 6;
    int lane = gtid & 63;
    if (node >= NN) return;
    float inv = 1.0f / fmaxf((float)g_deg[node], 1.0f);
    float o = -INFINITY;
    if (lane < COUT) {
        float s = 0.f;
#pragma unroll
        for (int k = 0; k < CH; ++k)
            s += g_agg2[(size_t)node * CH + k] * W2[k * COUT + lane];
        o = s * inv + b2[lane];
    }
    float m = o;
#pragma unroll
    for (int off = 32; off > 0; off >>= 1) m = fmaxf(m, __shfl_xor(m, off, 64));
    float ex = (lane < COUT) ? expf(o - m) : 0.0f;
    float ssum = ex;
#pragma unroll
    for (int off = 32; off > 0; off >>= 1) ssum += __shfl_xor(ssum, off, 64);
    if (lane < COUT) out[(size_t)node * COUT + lane] = o - m - logf(ssum);
}

extern "C" void kernel_launch(void* const* d_in, const int* in_sizes, int n_in,
                              void* d_out, int out_size, void* d_ws, size_t ws_size,
                              hipStream_t stream) {
    (void)d_ws; (void)ws_size;
    float* out = (float*)d_out;

    // Validate assumed input layout; on mismatch report cleanly instead of faulting.
    const int expect[6] = {NN * CIN, 2 * NE, CIN * CH, CH, CH * COUT, COUT};
    bool ok = (n_in >= 6) && (out_size == NN * COUT);
    if (ok) {
        for (int i = 0; i < 6; ++i)
            if (in_sizes[i] != expect[i]) { ok = false; break; }
    }
    if (!ok) {
        int n = out_size > 0 ? out_size : 1;
        fallback_zero_out_k<<<(n + 255) / 256, 256, 0, stream>>>(out, n);
        return;
    }

    const float* x  = (const float*)d_in[0];
    const int*   ei = (const int*)d_in[1];
    const float* W1 = (const float*)d_in[2];
    const float* b1 = (const float*)d_in[3];
    const float* W2 = (const float*)d_in[4];
    const float* b2 = (const float*)d_in[5];

    count_k  <<<EB, 256, 0, stream>>>(ei);
    scanA_k  <<<NB, 256, 0, stream>>>();
    scanB_k  <<<1, 1024, 0, stream>>>();
    scatter_k<<<EB, 256, 0, stream>>>(ei);
    build_k  <<<NB, 256, 0, stream>>>();
    gemm1_k  <<<(NN + TB - 1) / TB, TB, 0, stream>>>(x, W1);
    gather1_k<<<(NN * 4 + 255) / 256, 256, 0, stream>>>(b1);
    gather2_k<<<(NN * 4 + 255) / 256, 256, 0, stream>>>();
    final_k  <<<(NN * 64 + 255) / 256, 256, 0, stream>>>(W2, b2, out);
}

// Round 4
// 616.282 us; speedup vs baseline: 1.8918x; 1.0809x over previous
//
#include <hip/hip_runtime.h>
#include <cmath>

#define NN 100000     // nodes
#define NE 3200000    // edges
#define CIN 602
#define CH 16
#define COUT 41
#define TB 128        // gemm rows per block (= threads per block)
#define KTL 32        // gemm k-tile

// ---- counting-sort CSR build (no global atomics) ----
#define NPB 128                             // nodes per coarse bucket (pow2: dst>>7)
#define NB  ((NN + NPB - 1) / NPB)          // 782 buckets
#define EPC 32                              // edges per thread in count/scatter
#define ECHUNK (256 * EPC)                  // 8192 edges per block
#define EB  ((NE + ECHUNK - 1) / ECHUNK)    // 391 edge-chunk blocks

// Module-static scratch (independent of ws_size).
__device__ float g_h1[NN * CH];     // x @ W1
__device__ float g_h1b[NN * CH];    // relu(mean(agg1)+b1)
__device__ int   g_rs[NN + 1];      // CSR row_start (by dst)
__device__ int   g_csr[NE];         // src node per edge, grouped by dst
__device__ int2  g_pair[NE];        // (src,dst) pairs grouped by coarse bucket
__device__ int   g_cnt[NB * EB];    // per-(bucket,block) counts -> exclusive offsets
__device__ int   g_colsum[NB];      // edges per bucket
__device__ int   g_bbase[NB + 1];   // exclusive scan of g_colsum

__device__ __forceinline__ int clamp_node(int v) {
    return v < 0 ? 0 : (v >= NN ? NN - 1 : v);
}

// ---------------- fallback: if input layout differs, just zero d_out ----------
__global__ __launch_bounds__(256) void fallback_zero_out_k(float* __restrict__ out, int n) {
    int i = blockIdx.x * blockDim.x + threadIdx.x;
    if (i < n) out[i] = 0.0f;
}

// ---------------- pass 1: per-block histogram over coarse buckets (LDS) ------
__global__ __launch_bounds__(256) void count_k(const int* __restrict__ ei) {
    __shared__ int h[NB];
    const int t = threadIdx.x;
    for (int i = t; i < NB; i += 256) h[i] = 0;
    __syncthreads();
    const int base = blockIdx.x * ECHUNK;
#pragma unroll
    for (int j = 0; j < EPC; ++j) {
        int e = base + j * 256 + t;
        if (e < NE) {
            int d = clamp_node(ei[NE + e]);
            atomicAdd(&h[d >> 7], 1);
        }
    }
    __syncthreads();
    for (int i = t; i < NB; i += 256) g_cnt[i * EB + blockIdx.x] = h[i];
}

// ---------------- pass 2a: per-bucket scan over the 391 block counts ---------
__global__ __launch_bounds__(256) void scanA_k() {
    const int b = blockIdx.x;
    const int t = threadIdx.x;
    __shared__ int a[512];
    __shared__ int sh[256];
    a[t]       = (t < EB)       ? g_cnt[b * EB + t]       : 0;
    a[t + 256] = (t + 256 < EB) ? g_cnt[b * EB + t + 256] : 0;
    __syncthreads();
    int e0 = a[2 * t], e1 = a[2 * t + 1];
    int sum = e0 + e1;
    sh[t] = sum;
    __syncthreads();
    for (int off = 1; off < 256; off <<= 1) {   // Hillis-Steele inclusive
        int v = (t >= off) ? sh[t - off] : 0;
        __syncthreads();
        sh[t] += v;
        __syncthreads();
    }
    int run = sh[t] - sum;                       // exclusive offset of pair {2t,2t+1}
    if (2 * t < EB)     g_cnt[b * EB + 2 * t]     = run;
    if (2 * t + 1 < EB) g_cnt[b * EB + 2 * t + 1] = run + e0;
    if (t == 255) g_colsum[b] = sh[255];
}

// ---------------- pass 2b: scan bucket totals -> bucket bases ----------------
__global__ __launch_bounds__(1024) void scanB_k() {
    const int t = threadIdx.x;
    __shared__ int sh[1024];
    int v = (t < NB) ? g_colsum[t] : 0;
    sh[t] = v;
    __syncthreads();
    for (int off = 1; off < 1024; off <<= 1) {
        int u = (t >= off) ? sh[t - off] : 0;
        __syncthreads();
        sh[t] += u;
        __syncthreads();
    }
    if (t < NB) g_bbase[t] = sh[t] - v;          // exclusive
    if (t == 1023) {
        g_bbase[NB] = sh[1023];                  // == NE
        g_rs[NN]    = sh[1023];
    }
}

// ---------------- pass 3: scatter edges into bucket-grouped order ------------
__global__ __launch_bounds__(256) void scatter_k(const int* __restrict__ ei) {
    __shared__ int lb[NB];     // absolute next-write position per bucket
    const int t = threadIdx.x;
    for (int i = t; i < NB; i += 256)
        lb[i] = g_bbase[i] + g_cnt[i * EB + blockIdx.x];
    __syncthreads();
    const int base = blockIdx.x * ECHUNK;
#pragma unroll
    for (int j = 0; j < EPC; ++j) {
        int e = base + j * 256 + t;
        if (e < NE) {
            int s = clamp_node(ei[e]);
            int d = clamp_node(ei[NE + e]);
            int p = atomicAdd(&lb[d >> 7], 1);
            g_pair[p] = make_int2(s, d);
        }
    }
}

// ---------------- pass 4: per-bucket CSR finalize (LDS hist + scan + rank) ---
__global__ __launch_bounds__(256) void build_k() {
    const int b = blockIdx.x;
    const int t = threadIdx.x;
    const int n0 = b * NPB;
    const int e0 = g_bbase[b], e1 = g_bbase[b + 1];
    __shared__ int ldeg[NPB];
    __shared__ int lrs[NPB + 1];
    __shared__ int lcur[NPB];
    if (t < NPB) ldeg[t] = 0;
    __syncthreads();
    for (int e = e0 + t; e < e1; e += 256) {
        int2 p = g_pair[e];
        atomicAdd(&ldeg[p.y - n0], 1);
    }
    __syncthreads();
    if (t == 0) {
        int run = 0;
        for (int i = 0; i < NPB; ++i) { lrs[i] = run; run += ldeg[i]; }
        lrs[NPB] = run;
    }
    __syncthreads();
    if (t < NPB) {
        int node = n0 + t;
        if (node < NN) g_rs[node] = e0 + lrs[t];
        lcur[t] = lrs[t];
    }
    __syncthreads();
    for (int e = e0 + t; e < e1; e += 256) {
        int2 p = g_pair[e];
        int r = atomicAdd(&lcur[p.y - n0], 1);
        g_csr[e0 + r] = p.x;
    }
}

// ---------------- x @ W1 -> g_h1 ----------------
__global__ __launch_bounds__(TB) void gemm1_k(const float* __restrict__ x,
                                              const float* __restrict__ W1) {
    __shared__ float xs[KTL][TB + 1];  // stride 129: staging stores & reads <=2-way
    const int t = threadIdx.x;
    const int l  = t & 15;             // staging lane within row: kk pair {2l,2l+1}
    const int rg = t >> 4;             // staging row group: rows rg, rg+8, ...
    const int row0 = blockIdx.x * TB;
    const int row  = row0 + t;         // compute row owned by this thread

    float acc[CH];
#pragma unroll
    for (int c = 0; c < CH; ++c) acc[c] = 0.f;

    float2 ld[16];

    auto stage_load = [&](int kb) {
#pragma unroll
        for (int p = 0; p < 16; ++p) {
            int rgl = row0 + rg + 8 * p;
            ld[p] = (rgl < NN)
                ? *reinterpret_cast<const float2*>(x + (size_t)rgl * CIN + kb + 2 * l)
                : make_float2(0.f, 0.f);
        }
    };
    auto stage_load_ep = [&]() {
#pragma unroll
        for (int p = 0; p < 16; ++p) {
            int rgl = row0 + rg + 8 * p;
            ld[p] = (rgl < NN && l <= 12)
                ? *reinterpret_cast<const float2*>(x + (size_t)rgl * CIN + 576 + 2 * l)
                : make_float2(0.f, 0.f);
        }
    };
    auto stage_store = [&]() {
#pragma unroll
        for (int p = 0; p < 16; ++p) {
            int rl = rg + 8 * p;
            xs[2 * l][rl]     = ld[p].x;
            xs[2 * l + 1][rl] = ld[p].y;
        }
    };

    stage_load(0);
    for (int ti = 0; ti < 18; ++ti) {
        stage_store();
        __syncthreads();
        if (ti < 17) stage_load(KTL * (ti + 1)); else stage_load_ep();
        const int kb = KTL * ti;
#pragma unroll 8
        for (int kk = 0; kk < KTL; ++kk) {
            float xv = xs[kk][t];
            const float4* w4 = reinterpret_cast<const float4*>(W1 + (size_t)(kb + kk) * CH);
            float4 w0 = w4[0], w1 = w4[1], w2 = w4[2], w3 = w4[3];
            acc[0]  += xv * w0.x; acc[1]  += xv * w0.y; acc[2]  += xv * w0.z; acc[3]  += xv * w0.w;
            acc[4]  += xv * w1.x; acc[5]  += xv * w1.y; acc[6]  += xv * w1.z; acc[7]  += xv * w1.w;
            acc[8]  += xv * w2.x; acc[9]  += xv * w2.y; acc[10] += xv * w2.z; acc[11] += xv * w2.w;
            acc[12] += xv * w3.x; acc[13] += xv * w3.y; acc[14] += xv * w3.z; acc[15] += xv * w3.w;
        }
        __syncthreads();
    }
    stage_store();
    __syncthreads();
#pragma unroll 13
    for (int kk = 0; kk < 26; ++kk) {
        float xv = xs[kk][t];
        const float4* w4 = reinterpret_cast<const float4*>(W1 + (size_t)(576 + kk) * CH);
        float4 w0 = w4[0], w1 = w4[1], w2 = w4[2], w3 = w4[3];
        acc[0]  += xv * w0.x; acc[1]  += xv * w0.y; acc[2]  += xv * w0.z; acc[3]  += xv * w0.w;
        acc[4]  += xv * w1.x; acc[5]  += xv * w1.y; acc[6]  += xv * w1.z; acc[7]  += xv * w1.w;
        acc[8]  += xv * w2.x; acc[9]  += xv * w2.y; acc[10] += xv * w2.z; acc[11] += xv * w2.w;
        acc[12] += xv * w3.x; acc[13] += xv * w3.y; acc[14] += xv * w3.z; acc[15] += xv * w3.w;
    }

    if (row < NN) {
        float4* hp = reinterpret_cast<float4*>(g_h1 + (size_t)row * CH);
        hp[0] = make_float4(acc[0],  acc[1],  acc[2],  acc[3]);
        hp[1] = make_float4(acc[4],  acc[5],  acc[6],  acc[7]);
        hp[2] = make_float4(acc[8],  acc[9],  acc[10], acc[11]);
        hp[3] = make_float4(acc[12], acc[13], acc[14], acc[15]);
    }
}

// ---------------- layer-1 gather: h1b = relu(mean_{e->n} h1[src] + b1) -------
// ONE WAVE PER NODE: 64 lanes = 16 edge-slots x 4 channel-quads. A degree-32
// node completes its edge loop in 1 unrolled iteration (2 independent 64B row
// reads in flight per 4-lane group) instead of ~8 dependent L2/L3 round trips.
// Cross-lane reduce over edge-slots via __shfl_xor {4,8,16,32}.
__global__ __launch_bounds__(256) void gather1_k(const float* __restrict__ b1) {
    int gtid = blockIdx.x * blockDim.x + threadIdx.x;
    int node = gtid >> 6;               // grid sized exactly: node < NN always
    int l    = gtid & 63;
    int q    = l & 3;                   // channel quad (channels 4q..4q+3)
    int es   = l >> 2;                  // edge slot 0..15
    int start = g_rs[node], end = g_rs[node + 1];
    float4 acc = make_float4(0.f, 0.f, 0.f, 0.f);
    int e = start + es;
    for (; e + 16 < end; e += 32) {
        int s0 = g_csr[e], s1 = g_csr[e + 16];
        float4 a = *reinterpret_cast<const float4*>(&g_h1[(size_t)s0 * CH + (q << 2)]);
        float4 b = *reinterpret_cast<const float4*>(&g_h1[(size_t)s1 * CH + (q << 2)]);
        acc.x += a.x + b.x; acc.y += a.y + b.y;
        acc.z += a.z + b.z; acc.w += a.w + b.w;
    }
    if (e < end) {
        int s0 = g_csr[e];
        float4 a = *reinterpret_cast<const float4*>(&g_h1[(size_t)s0 * CH + (q << 2)]);
        acc.x += a.x; acc.y += a.y; acc.z += a.z; acc.w += a.w;
    }
#pragma unroll
    for (int off = 4; off < 64; off <<= 1) {
        acc.x += __shfl_xor(acc.x, off, 64);
        acc.y += __shfl_xor(acc.y, off, 64);
        acc.z += __shfl_xor(acc.z, off, 64);
        acc.w += __shfl_xor(acc.w, off, 64);
    }
    if (l < 4) {                         // lane l writes quad q == l
        float inv = 1.0f / fmaxf((float)(end - start), 1.0f);
        float4 bv = reinterpret_cast<const float4*>(b1)[l];
        float4 r;
        r.x = fmaxf(acc.x * inv + bv.x, 0.f);
        r.y = fmaxf(acc.y * inv + bv.y, 0.f);
        r.z = fmaxf(acc.z * inv + bv.z, 0.f);
        r.w = fmaxf(acc.w * inv + bv.w, 0.f);
        reinterpret_cast<float4*>(g_h1b)[(size_t)node * 4 + l] = r;
    }
}

// ---------------- fused layer-2 gather + W2 matvec + log_softmax -------------
// Wave per node: gather/reduce agg2 into registers, broadcast the 16 channels
// via __shfl from lanes 0..3 (v_readlane -> SGPR), W2 staged in LDS, then
// in-wave softmax. Eliminates final_k and the g_agg2 round-trip.
__global__ __launch_bounds__(256) void g2final_k(const float* __restrict__ W2,
                                                 const float* __restrict__ b2,
                                                 float* __restrict__ out) {
    __shared__ float w2s[CH * COUT];     // 16 x 41
    const int t = threadIdx.x;
    for (int i = t; i < CH * COUT; i += 256) w2s[i] = W2[i];
    __syncthreads();

    int gtid = blockIdx.x * blockDim.x + t;
    int node = gtid >> 6;                // grid sized exactly: node < NN always
    int l    = gtid & 63;
    int q    = l & 3;
    int es   = l >> 2;
    int start = g_rs[node], end = g_rs[node + 1];
    float4 acc = make_float4(0.f, 0.f, 0.f, 0.f);
    int e = start + es;
    for (; e + 16 < end; e += 32) {
        int s0 = g_csr[e], s1 = g_csr[e + 16];
        float4 a = *reinterpret_cast<const float4*>(&g_h1b[(size_t)s0 * CH + (q << 2)]);
        float4 b = *reinterpret_cast<const float4*>(&g_h1b[(size_t)s1 * CH + (q << 2)]);
        acc.x += a.x + b.x; acc.y += a.y + b.y;
        acc.z += a.z + b.z; acc.w += a.w + b.w;
    }
    if (e < end) {
        int s0 = g_csr[e];
        float4 a = *reinterpret_cast<const float4*>(&g_h1b[(size_t)s0 * CH + (q << 2)]);
        acc.x += a.x; acc.y += a.y; acc.z += a.z; acc.w += a.w;
    }
#pragma unroll
    for (int off = 4; off < 64; off <<= 1) {
        acc.x += __shfl_xor(acc.x, off, 64);
        acc.y += __shfl_xor(acc.y, off, 64);
        acc.z += __shfl_xor(acc.z, off, 64);
        acc.w += __shfl_xor(acc.w, off, 64);
    }
    // broadcast all 16 agg channels to every lane (source lanes 0..3 hold
    // the reduced quads; compile-time lane -> v_readlane, SGPR broadcast)
    float a16[CH];
#pragma unroll
    for (int k = 0; k < CH; ++k) {
        float comp = ((k & 3) == 0) ? acc.x : ((k & 3) == 1) ? acc.y
                   : ((k & 3) == 2) ? acc.z : acc.w;
        a16[k] = __shfl(comp, k >> 2, 64);
    }
    float inv = 1.0f / fmaxf((float)(end - start), 1.0f);
    float o = -INFINITY;
    if (l < COUT) {
        float s = 0.f;
#pragma unroll
        for (int k = 0; k < CH; ++k) s += a16[k] * w2s[k * COUT + l];
        o = s * inv + b2[l];
    }
    float m = o;
#pragma unroll
    for (int off = 32; off > 0; off >>= 1) m = fmaxf(m, __shfl_xor(m, off, 64));
    float ex = (l < COUT) ? expf(o - m) : 0.0f;
    float ssum = ex;
#pragma unroll
    for (int off = 32; off > 0; off >>= 1) ssum += __shfl_xor(ssum, off, 64);
    if (l < COUT) out[(size_t)node * COUT + l] = o - m - logf(ssum);
}

extern "C" void kernel_launch(void* const* d_in, const int* in_sizes, int n_in,
                              void* d_out, int out_size, void* d_ws, size_t ws_size,
                              hipStream_t stream) {
    (void)d_ws; (void)ws_size;
    float* out = (float*)d_out;

    // Validate assumed input layout; on mismatch report cleanly instead of faulting.
    const int expect[6] = {NN * CIN, 2 * NE, CIN * CH, CH, CH * COUT, COUT};
    bool ok = (n_in >= 6) && (out_size == NN * COUT);
    if (ok) {
        for (int i = 0; i < 6; ++i)
            if (in_sizes[i] != expect[i]) { ok = false; break; }
    }
    if (!ok) {
        int n = out_size > 0 ? out_size : 1;
        fallback_zero_out_k<<<(n + 255) / 256, 256, 0, stream>>>(out, n);
        return;
    }

    const float* x  = (const float*)d_in[0];
    const int*   ei = (const int*)d_in[1];
    const float* W1 = (const float*)d_in[2];
    const float* b1 = (const float*)d_in[3];
    const float* W2 = (const float*)d_in[4];
    const float* b2 = (const float*)d_in[5];

    const int WAVE_BLKS = (NN * 64 + 255) / 256;   // one wave per node

    count_k  <<<EB, 256, 0, stream>>>(ei);
    scanA_k  <<<NB, 256, 0, stream>>>();
    scanB_k  <<<1, 1024, 0, stream>>>();
    scatter_k<<<EB, 256, 0, stream>>>(ei);
    build_k  <<<NB, 256, 0, stream>>>();
    gemm1_k  <<<(NN + TB - 1) / TB, TB, 0, stream>>>(x, W1);
    gather1_k<<<WAVE_BLKS, 256, 0, stream>>>(b1);
    g2final_k<<<WAVE_BLKS, 256, 0, stream>>>(W2, b2, out);
}